// Round 1
// baseline (1647.911 us; speedup 1.0000x reference)
//
#include <hip/hip_runtime.h>
#include <math.h>

#define B_    16
#define C_    64
#define HW_   512
#define KS_   15
#define HALO  7
#define TS    64          // output tile: 64x64
#define INW   78          // TS + 2*HALO
#define INS   80          // padded LDS stride for input tile (16B-aligned rows)

// ---------------------------------------------------------------------------
// Filter coefficient precompute: filter_c = A⊗A - B⊗B with
//   A[i] = f2 * sinc(pi*f2*(i-7)) * hamming[i]
//   B[i] = f1 * sinc(pi*f1*(i-7)) * hamming[i]
// Layout in ws: coefs[c*32 + i] = A, coefs[c*32 + 16 + i] = B
// ---------------------------------------------------------------------------
__global__ void make_filters(const float* __restrict__ f1,
                             const float* __restrict__ band,
                             float* __restrict__ coefs) {
    int c = threadIdx.x;
    if (c >= C_) return;
    float F1 = f1[c];
    float F2 = F1 + fabsf(band[c]);
    const float PI = 3.14159265358979323846f;
    #pragma unroll
    for (int i = 0; i < KS_; ++i) {
        // hamming: n = linspace(0,15,15) -> 0.54 - 0.46*cos(2*pi*i/14)
        float h = 0.54f - 0.46f * cosf((2.0f * PI / 14.0f) * (float)i);
        float y1, y2;
        if (i == HALO) {
            y1 = 1.0f; y2 = 1.0f;
        } else {
            float t  = (float)(i - HALO);
            float a1 = PI * F1 * t;
            float a2 = PI * F2 * t;
            y1 = sinf(a1) / a1;
            y2 = sinf(a2) / a2;
        }
        coefs[c * 32 + i]       = F2 * y2 * h;
        coefs[c * 32 + 16 + i]  = F1 * y1 * h;
    }
}

// ---------------------------------------------------------------------------
// Separable conv: out = Av(Ah(x)) - Bv(Bh(x)), SAME zero padding.
// One block = one 64x64 tile of one (batch, channel).
// ---------------------------------------------------------------------------
__global__ __launch_bounds__(256, 3)
void sinc_conv(const float* __restrict__ x,
               const float* __restrict__ coefs,
               float* __restrict__ out) {
    __shared__ __align__(16) float s_in[INW * INS];  // input tile + halo
    __shared__ __align__(16) float s_h[INW * TS];    // horizontal-conv buffer

    const int tid  = threadIdx.x;
    const int bid  = blockIdx.x;
    const int ch   = bid & 63;            // channel fastest: 64 consecutive
    const int tile = (bid >> 6) & 63;     //   blocks share one input tile (L2)
    const int b    = bid >> 12;
    const int tx   = (tile & 7) * TS;
    const int ty   = (tile >> 3) * TS;

    // per-channel 1-D coefficients (uniform addresses -> scalar loads)
    float cA[KS_], cB[KS_];
    #pragma unroll
    for (int i = 0; i < KS_; ++i) {
        cA[i] = coefs[ch * 32 + i];
        cB[i] = coefs[ch * 32 + 16 + i];
    }

    // ---- stage input tile (with halo, zero-padded at borders) ----
    const float* xb = x + (size_t)b * (HW_ * HW_);
    for (int idx = tid; idx < INW * INS; idx += 256) {
        int r  = idx / INS;
        int c  = idx - r * INS;
        int gy = ty + r - HALO;
        int gx = tx + c - HALO;
        float v = 0.0f;
        if (c < INW && (unsigned)gy < (unsigned)HW_ && (unsigned)gx < (unsigned)HW_)
            v = xb[gy * HW_ + gx];
        s_in[idx] = v;
    }
    __syncthreads();

    // ---- horizontal conv pass: s_h[r][c] = sum_k cf[k] * s_in[r][c+k] ----
    auto hconv = [&](const float* cf) {
        for (int task = tid; task < INW * 4; task += 256) {
            int r  = task >> 2;
            int cb = (task & 3) * 16;     // 16 outputs per task
            float w[32];
            #pragma unroll
            for (int m = 0; m < 8; ++m)
                *(float4*)(w + 4 * m) =
                    *(const float4*)(s_in + r * INS + cb + 4 * m);
            float o[16];
            #pragma unroll
            for (int j = 0; j < 16; ++j) {
                float s = cf[0] * w[j];
                #pragma unroll
                for (int k = 1; k < KS_; ++k)
                    s = fmaf(cf[k], w[j + k], s);
                o[j] = s;
            }
            #pragma unroll
            for (int m = 0; m < 4; ++m)
                *(float4*)(s_h + r * TS + cb + 4 * m) = *(float4*)(o + 4 * m);
        }
    };

    float acc[16];
    #pragma unroll
    for (int j = 0; j < 16; ++j) acc[j] = 0.0f;

    // ---- vertical conv pass: acc[j] (+/-)= sum_k cf[k] * s_h[r0+j+k][c] ----
    const int c_out = tid & 63;
    const int r0    = (tid >> 6) * 16;
    auto vconv = [&](const float* cf, bool sub) {
        #pragma unroll
        for (int r = 0; r < TS / 4 + KS_ - 1; ++r) {   // 30 rows
            float v = s_h[(r0 + r) * TS + c_out];
            if (sub) v = -v;
            #pragma unroll
            for (int j = 0; j < 16; ++j) {
                int k = r - j;
                if (k >= 0 && k < KS_)
                    acc[j] = fmaf(cf[k], v, acc[j]);
            }
        }
    };

    hconv(cA);
    __syncthreads();
    vconv(cA, false);
    __syncthreads();            // before overwriting s_h
    hconv(cB);
    __syncthreads();
    vconv(cB, true);

    // ---- store 16 rows x 1 col per thread, lane-consecutive columns ----
    float* ob = out + (((size_t)b * C_ + ch) * HW_ + (ty + r0)) * (size_t)HW_
                + tx + c_out;
    #pragma unroll
    for (int j = 0; j < 16; ++j)
        ob[(size_t)j * HW_] = acc[j];
}

extern "C" void kernel_launch(void* const* d_in, const int* in_sizes, int n_in,
                              void* d_out, int out_size, void* d_ws, size_t ws_size,
                              hipStream_t stream) {
    const float* x    = (const float*)d_in[0];
    const float* f1   = (const float*)d_in[1];
    const float* band = (const float*)d_in[2];
    float* coefs = (float*)d_ws;
    float* outp  = (float*)d_out;

    hipLaunchKernelGGL(make_filters, dim3(1), dim3(64), 0, stream,
                       f1, band, coefs);

    int nblocks = B_ * C_ * (HW_ / TS) * (HW_ / TS);   // 65536
    hipLaunchKernelGGL(sinc_conv, dim3(nblocks), dim3(256), 0, stream,
                       x, coefs, outp);
}

// Round 2
// 1489.348 us; speedup vs baseline: 1.1065x; 1.1065x over previous
//
#include <hip/hip_runtime.h>
#include <math.h>

#define B_    16
#define C_    64
#define HW_   512
#define KS_   15
#define HALO  7
#define TS    64          // output tile: 64x64
#define INW   78          // TS + 2*HALO
#define INS   84          // s_in stride: 84 words = 21 x 16B (odd # of superbanks)
#define SHS   68          // s_h  stride: 68 words = 17 x 16B (odd # of superbanks)

// ---------------------------------------------------------------------------
// Filter coefficient precompute: filter_c = A⊗A - B⊗B with
//   A[i] = f2 * sinc(pi*f2*(i-7)) * hamming[i]
//   B[i] = f1 * sinc(pi*f1*(i-7)) * hamming[i]
// Layout in ws: coefs[c*32 + i] = A, coefs[c*32 + 16 + i] = B
// ---------------------------------------------------------------------------
__global__ void make_filters(const float* __restrict__ f1,
                             const float* __restrict__ band,
                             float* __restrict__ coefs) {
    int c = threadIdx.x;
    if (c >= C_) return;
    float F1 = f1[c];
    float F2 = F1 + fabsf(band[c]);
    const float PI = 3.14159265358979323846f;
    #pragma unroll
    for (int i = 0; i < KS_; ++i) {
        float h = 0.54f - 0.46f * cosf((2.0f * PI / 14.0f) * (float)i);
        float y1, y2;
        if (i == HALO) {
            y1 = 1.0f; y2 = 1.0f;
        } else {
            float t  = (float)(i - HALO);
            float a1 = PI * F1 * t;
            float a2 = PI * F2 * t;
            y1 = sinf(a1) / a1;
            y2 = sinf(a2) / a2;
        }
        coefs[c * 32 + i]       = F2 * y2 * h;
        coefs[c * 32 + 16 + i]  = F1 * y1 * h;
    }
}

// ---------------------------------------------------------------------------
// Separable conv: out = Av(Ah(x)) - Bv(Bh(x)), SAME zero padding.
// One block = one 64x64 tile of one (batch, channel).
// ---------------------------------------------------------------------------
__global__ __launch_bounds__(256, 3)
void sinc_conv(const float* __restrict__ x,
               const float* __restrict__ coefs,
               float* __restrict__ out) {
    __shared__ __align__(16) float s_in[INW * INS];  // input tile + halo
    __shared__ __align__(16) float s_h[INW * SHS];   // horizontal-conv buffer

    const int tid  = threadIdx.x;
    const int bid  = blockIdx.x;
    const int ch   = bid & 63;            // channel fastest: 64 consecutive
    const int tile = (bid >> 6) & 63;     //   blocks share one input tile (L2)
    const int b    = bid >> 12;
    const int tx   = (tile & 7) * TS;
    const int ty   = (tile >> 3) * TS;

    // per-channel 1-D coefficients (uniform addresses -> scalar loads)
    float cA[KS_], cB[KS_];
    #pragma unroll
    for (int i = 0; i < KS_; ++i) {
        cA[i] = coefs[ch * 32 + i];
        cB[i] = coefs[ch * 32 + 16 + i];
    }

    // ---- stage input tile (with halo, zero-padded at borders) ----
    const float* xb = x + (size_t)b * (HW_ * HW_);
    for (int idx = tid; idx < INW * INS; idx += 256) {
        int r  = idx / INS;
        int c  = idx - r * INS;
        int gy = ty + r - HALO;
        int gx = tx + c - HALO;
        float v = 0.0f;
        if (c < INW && (unsigned)gy < (unsigned)HW_ && (unsigned)gx < (unsigned)HW_)
            v = xb[gy * HW_ + gx];
        s_in[idx] = v;
    }
    __syncthreads();

    // ---- horizontal conv pass: s_h[r][c] = sum_k cf[k] * s_in[r][c+k] ----
    auto hconv = [&](const float* cf) {
        for (int task = tid; task < INW * 4; task += 256) {
            int r  = task >> 2;
            int cb = (task & 3) * 16;     // 16 outputs per task
            float w[32];
            #pragma unroll
            for (int m = 0; m < 8; ++m)
                *(float4*)(w + 4 * m) =
                    *(const float4*)(s_in + r * INS + cb + 4 * m);
            float o[16];
            #pragma unroll
            for (int j = 0; j < 16; ++j) {
                float s = cf[0] * w[j];
                #pragma unroll
                for (int k = 1; k < KS_; ++k)
                    s = fmaf(cf[k], w[j + k], s);
                o[j] = s;
            }
            #pragma unroll
            for (int m = 0; m < 4; ++m)
                *(float4*)(s_h + r * SHS + cb + 4 * m) = *(float4*)(o + 4 * m);
        }
    };

    float acc[16];
    #pragma unroll
    for (int j = 0; j < 16; ++j) acc[j] = 0.0f;

    // ---- vertical conv pass: acc[j] (+/-)= sum_k cf[k] * s_h[r0+j+k][c] ----
    const int c_out = tid & 63;
    const int r0    = (tid >> 6) * 16;
    auto vconv = [&](const float* cf, bool sub) {
        #pragma unroll
        for (int r = 0; r < TS / 4 + KS_ - 1; ++r) {   // 30 rows
            float v = s_h[(r0 + r) * SHS + c_out];
            if (sub) v = -v;
            #pragma unroll
            for (int j = 0; j < 16; ++j) {
                int k = r - j;
                if (k >= 0 && k < KS_)
                    acc[j] = fmaf(cf[k], v, acc[j]);
            }
        }
    };

    hconv(cA);
    __syncthreads();
    vconv(cA, false);
    __syncthreads();            // before overwriting s_h
    hconv(cB);
    __syncthreads();
    vconv(cB, true);

    // ---- store 16 rows x 1 col per thread, lane-consecutive columns ----
    float* ob = out + (((size_t)b * C_ + ch) * HW_ + (ty + r0)) * (size_t)HW_
                + tx + c_out;
    #pragma unroll
    for (int j = 0; j < 16; ++j)
        ob[(size_t)j * HW_] = acc[j];
}

extern "C" void kernel_launch(void* const* d_in, const int* in_sizes, int n_in,
                              void* d_out, int out_size, void* d_ws, size_t ws_size,
                              hipStream_t stream) {
    const float* x    = (const float*)d_in[0];
    const float* f1   = (const float*)d_in[1];
    const float* band = (const float*)d_in[2];
    float* coefs = (float*)d_ws;
    float* outp  = (float*)d_out;

    hipLaunchKernelGGL(make_filters, dim3(1), dim3(64), 0, stream,
                       f1, band, coefs);

    int nblocks = B_ * C_ * (HW_ / TS) * (HW_ / TS);   // 65536
    hipLaunchKernelGGL(sinc_conv, dim3(nblocks), dim3(256), 0, stream,
                       x, coefs, outp);
}

// Round 3
// 1100.395 us; speedup vs baseline: 1.4976x; 1.3535x over previous
//
#include <hip/hip_runtime.h>
#include <math.h>

#define B_    16
#define C_    64
#define HW_   512
#define KS_   15
#define HALO  7
#define TS    64          // output tile: 64x64
#define INW   78          // TS + 2*HALO rows for hconv
#define INS   84          // fallback s_in stride (21 x 16B)
#define SHS   68          // s_h stride: 68 words = 17 x 16B (odd # superbanks)
#define PROW  528         // padded row: 7 + 512 + 9
#define PADOFF 2048       // float offset of padded image inside ws (8 KB for coefs)

// ---------------------------------------------------------------------------
// coefs[c*32 + i]      =  F2*sinc(pi*F2*(i-7))*hamming[i]      (A)
// coefs[c*32 + 16 + i] = -F1*sinc(pi*F1*(i-7))*hamming[i]      (-B)
// Storing -B lets both the hconv-B pass and the final subtraction fold into
// FMA sign modifiers:  out = vconv(+A, hconv(A)) + vconv(+B, hconv(-B)).
// ---------------------------------------------------------------------------
__global__ void make_filters(const float* __restrict__ f1,
                             const float* __restrict__ band,
                             float* __restrict__ coefs) {
    int c = threadIdx.x;
    if (c >= C_) return;
    float F1 = f1[c];
    float F2 = F1 + fabsf(band[c]);
    const float PI = 3.14159265358979323846f;
    #pragma unroll
    for (int i = 0; i < KS_; ++i) {
        float h = 0.54f - 0.46f * cosf((2.0f * PI / 14.0f) * (float)i);
        float y1, y2;
        if (i == HALO) {
            y1 = 1.0f; y2 = 1.0f;
        } else {
            float t  = (float)(i - HALO);
            float a1 = PI * F1 * t;
            float a2 = PI * F2 * t;
            y1 = sinf(a1) / a1;
            y2 = sinf(a2) / a2;
        }
        coefs[c * 32 + i]       =  F2 * y2 * h;
        coefs[c * 32 + 16 + i]  = -F1 * y1 * h;
    }
}

// ---------------------------------------------------------------------------
// Column-padded input copy: ws[PADOFF + row*528 + (gx+7)] = x[row*512 + gx]
// (zero outside). row = b*512 + y. 16B-aligned stores.
// ---------------------------------------------------------------------------
__global__ void pad_copy(const float* __restrict__ x, float* __restrict__ ws) {
    int t   = blockIdx.x * 256 + threadIdx.x;   // < 8192*132
    int pc4 = t % 132;
    int row = t / 132;
    const float* src = x + (size_t)row * HW_;
    int gx0 = pc4 * 4 - HALO;
    float v[4];
    #pragma unroll
    for (int e = 0; e < 4; ++e) {
        int gx = gx0 + e;
        v[e] = ((unsigned)gx < (unsigned)HW_) ? src[gx] : 0.0f;
    }
    *(float4*)(ws + PADOFF + (size_t)row * PROW + pc4 * 4) = *(float4*)v;
}

// ---------------------------------------------------------------------------
// Separable conv body. PAD=true: read input windows straight from the padded
// global copy (no s_in LDS -> 21 KB LDS -> 6-7 blocks/CU). PAD=false:
// fallback with LDS staging (47 KB, 3 blocks/CU).
// ---------------------------------------------------------------------------
template <bool PAD>
__device__ __forceinline__ void conv_body(const float* __restrict__ xsrc,
                                          const float* __restrict__ coefs,
                                          float* __restrict__ out) {
    __shared__ __align__(16) float s_h[INW * SHS];
    __shared__ __align__(16) float s_in_arr[PAD ? 4 : INW * INS];

    const int tid = threadIdx.x;
    const int bid = blockIdx.x;
    // XCD-aware swizzle (65536 = 8*8192, bijective): each XCD works a
    // contiguous range -> all 64 channel-blocks of a tile share one L2.
    const int wg   = (bid & 7) * 8192 + (bid >> 3);
    const int ch   = wg & 63;
    const int tile = (wg >> 6) & 63;
    const int b    = wg >> 12;
    const int tx   = (tile & 7) * TS;
    const int ty   = (tile >> 3) * TS;

    float cA[KS_], cB[KS_];          // cB holds -B
    #pragma unroll
    for (int i = 0; i < KS_; ++i) {
        cA[i] = coefs[ch * 32 + i];
        cB[i] = coefs[ch * 32 + 16 + i];
    }

    if constexpr (!PAD) {
        for (int idx = tid; idx < INW * INS; idx += 256) {
            int r  = idx / INS;
            int c  = idx - r * INS;
            int gy = ty + r - HALO;
            int gx = tx + c - HALO;
            float v = 0.0f;
            if (c < INW && (unsigned)gy < (unsigned)HW_ &&
                (unsigned)gx < (unsigned)HW_)
                v = xsrc[(size_t)b * HW_ * HW_ + (size_t)gy * HW_ + gx];
            s_in_arr[idx] = v;
        }
        __syncthreads();
    }

    // ---- horizontal pass: s_h[r][c] = sum_k cf[k] * in[r][c+k] ----
    auto hconv = [&](const float (&cf)[KS_]) {
        for (int task = tid; task < INW * 4; task += 256) {
            int r  = task >> 2;
            int cb = (task & 3) << 4;
            float w[32];
            if constexpr (PAD) {
                int gy = ty + r - HALO;
                if ((unsigned)gy < (unsigned)HW_) {
                    const float* src =
                        xsrc + ((size_t)b * HW_ + gy) * PROW + tx + cb;
                    #pragma unroll
                    for (int m = 0; m < 8; ++m)
                        *(float4*)(w + 4 * m) = *(const float4*)(src + 4 * m);
                } else {
                    #pragma unroll
                    for (int m = 0; m < 32; ++m) w[m] = 0.0f;
                }
            } else {
                #pragma unroll
                for (int m = 0; m < 8; ++m)
                    *(float4*)(w + 4 * m) =
                        *(const float4*)(s_in_arr + r * INS + cb + 4 * m);
            }
            float o[16];
            #pragma unroll
            for (int j = 0; j < 16; ++j) {
                float s = cf[0] * w[j];
                #pragma unroll
                for (int k = 1; k < KS_; ++k)
                    s = fmaf(cf[k], w[j + k], s);
                o[j] = s;
            }
            #pragma unroll
            for (int m = 0; m < 4; ++m)
                *(float4*)(s_h + r * SHS + cb + 4 * m) = *(float4*)(o + 4 * m);
        }
    };

    // ---- vertical pass: thread owns 8 rows x 2 cols; ds_read_b64 rows ----
    const int c2 = (tid & 31) * 2;
    const int rg = (tid >> 5) * 8;
    float acc[8][2];
    #pragma unroll
    for (int j = 0; j < 8; ++j) acc[j][0] = acc[j][1] = 0.0f;

    auto vconv = [&](const float (&cf)[KS_], float sgn) {
        #pragma unroll
        for (int r = 0; r < 8 + KS_ - 1; ++r) {   // 22 rows
            float2 v = *(const float2*)(s_h + (rg + r) * SHS + c2);
            #pragma unroll
            for (int j = 0; j < 8; ++j) {
                int k = r - j;
                if (k >= 0 && k < KS_) {
                    acc[j][0] = fmaf(sgn * cf[k], v.x, acc[j][0]);
                    acc[j][1] = fmaf(sgn * cf[k], v.y, acc[j][1]);
                }
            }
        }
    };

    hconv(cA);
    __syncthreads();
    vconv(cA, 1.0f);
    __syncthreads();              // before overwriting s_h
    hconv(cB);                    // conv with -B  -> s_h = -hB
    __syncthreads();
    vconv(cB, -1.0f);             // taps -(-B)=+B on -hB  -> subtracts B-term

    float* ob = out + (((size_t)b * C_ + ch) * HW_ + (ty + rg)) * (size_t)HW_
                + tx + c2;
    #pragma unroll
    for (int j = 0; j < 8; ++j) {
        float2 st = make_float2(acc[j][0], acc[j][1]);
        *(float2*)(ob + (size_t)j * HW_) = st;
    }
}

__global__ __launch_bounds__(256, 6)
void sinc_conv_pad(const float* __restrict__ xpad,
                   const float* __restrict__ coefs,
                   float* __restrict__ out) {
    conv_body<true>(xpad, coefs, out);
}

__global__ __launch_bounds__(256, 3)
void sinc_conv_lds(const float* __restrict__ x,
                   const float* __restrict__ coefs,
                   float* __restrict__ out) {
    conv_body<false>(x, coefs, out);
}

extern "C" void kernel_launch(void* const* d_in, const int* in_sizes, int n_in,
                              void* d_out, int out_size, void* d_ws, size_t ws_size,
                              hipStream_t stream) {
    const float* x    = (const float*)d_in[0];
    const float* f1   = (const float*)d_in[1];
    const float* band = (const float*)d_in[2];
    float* ws   = (float*)d_ws;
    float* outp = (float*)d_out;

    hipLaunchKernelGGL(make_filters, dim3(1), dim3(64), 0, stream,
                       f1, band, ws);

    const int nblocks = B_ * C_ * (HW_ / TS) * (HW_ / TS);   // 65536
    const size_t need = (size_t)PADOFF * 4 + (size_t)B_ * HW_ * PROW * 4;

    if (ws_size >= need) {
        hipLaunchKernelGGL(pad_copy, dim3(4224), dim3(256), 0, stream, x, ws);
        hipLaunchKernelGGL(sinc_conv_pad, dim3(nblocks), dim3(256), 0, stream,
                           ws + PADOFF, ws, outp);
    } else {
        hipLaunchKernelGGL(sinc_conv_lds, dim3(nblocks), dim3(256), 0, stream,
                           x, ws, outp);
    }
}

// Round 4
// 889.208 us; speedup vs baseline: 1.8532x; 1.2375x over previous
//
#include <hip/hip_runtime.h>
#include <math.h>

#define B_    16
#define C_    64
#define HW_   512
#define KS_   15
#define HALO  7
#define TS    64          // output tile: 64x64
#define INW   78          // TS + 2*HALO rows for hconv
#define INS   84          // fallback s_in stride (21 x 16B)
#define SHS   68          // s_h stride: 68 words = 17 x 16B (odd # superbanks)
#define PROW  528         // padded row: 7 + 512 + 9
#define PADOFF 2048       // float offset of padded image inside ws (8 KB for coefs)

// ---------------------------------------------------------------------------
// coefs[c*32 + i]      =  F2*sinc(pi*F2*(i-7))*hamming[i]      (A)
// coefs[c*32 + 16 + i] = -F1*sinc(pi*F1*(i-7))*hamming[i]      (-B)
// Storing -B lets the B-term subtraction fold into FMA sign modifiers.
// ---------------------------------------------------------------------------
__global__ void make_filters(const float* __restrict__ f1,
                             const float* __restrict__ band,
                             float* __restrict__ coefs) {
    int c = threadIdx.x;
    if (c >= C_) return;
    float F1 = f1[c];
    float F2 = F1 + fabsf(band[c]);
    const float PI = 3.14159265358979323846f;
    #pragma unroll
    for (int i = 0; i < KS_; ++i) {
        float h = 0.54f - 0.46f * cosf((2.0f * PI / 14.0f) * (float)i);
        float y1, y2;
        if (i == HALO) {
            y1 = 1.0f; y2 = 1.0f;
        } else {
            float t  = (float)(i - HALO);
            float a1 = PI * F1 * t;
            float a2 = PI * F2 * t;
            y1 = sinf(a1) / a1;
            y2 = sinf(a2) / a2;
        }
        coefs[c * 32 + i]       =  F2 * y2 * h;
        coefs[c * 32 + 16 + i]  = -F1 * y1 * h;
    }
}

// ---------------------------------------------------------------------------
// Column-padded input copy: ws[PADOFF + row*528 + (gx+7)] = x[row*512 + gx]
// ---------------------------------------------------------------------------
__global__ void pad_copy(const float* __restrict__ x, float* __restrict__ ws) {
    int t   = blockIdx.x * 256 + threadIdx.x;   // < 8192*132
    int pc4 = t % 132;
    int row = t / 132;
    const float* src = x + (size_t)row * HW_;
    int gx0 = pc4 * 4 - HALO;
    float v[4];
    #pragma unroll
    for (int e = 0; e < 4; ++e) {
        int gx = gx0 + e;
        v[e] = ((unsigned)gx < (unsigned)HW_) ? src[gx] : 0.0f;
    }
    *(float4*)(ws + PADOFF + (size_t)row * PROW + pc4 * 4) = *(float4*)v;
}

// ---------------------------------------------------------------------------
// Separable conv body. PAD=true: read input windows straight from the padded
// global copy (no s_in LDS -> 21 KB LDS -> 6 blocks/CU). Natural block order:
// ch fastest so the 64 channel-blocks of a tile are temporally adjacent ->
// whichever XCDs they land on fetch the tile once (R2-proven: 67 MB FETCH).
// ---------------------------------------------------------------------------
template <bool PAD>
__device__ __forceinline__ void conv_body(const float* __restrict__ xsrc,
                                          const float* __restrict__ coefs,
                                          float* __restrict__ out) {
    __shared__ __align__(16) float s_h[INW * SHS];
    __shared__ __align__(16) float s_in_arr[PAD ? 4 : INW * INS];

    const int tid  = threadIdx.x;
    const int bid  = blockIdx.x;
    const int ch   = bid & 63;            // channel fastest
    const int tile = (bid >> 6) & 63;
    const int b    = bid >> 12;
    const int tx   = (tile & 7) * TS;
    const int ty   = (tile >> 3) * TS;

    float cA[KS_], cB[KS_];               // cB holds -B
    #pragma unroll
    for (int i = 0; i < KS_; ++i) {
        cA[i] = coefs[ch * 32 + i];
        cB[i] = coefs[ch * 32 + 16 + i];
    }

    if constexpr (!PAD) {
        for (int idx = tid; idx < INW * INS; idx += 256) {
            int r  = idx / INS;
            int c  = idx - r * INS;
            int gy = ty + r - HALO;
            int gx = tx + c - HALO;
            float v = 0.0f;
            if (c < INW && (unsigned)gy < (unsigned)HW_ &&
                (unsigned)gx < (unsigned)HW_)
                v = xsrc[(size_t)b * HW_ * HW_ + (size_t)gy * HW_ + gx];
            s_in_arr[idx] = v;
        }
        __syncthreads();
    }

    // ---- horizontal pass: s_h[r][c] = sum_k cf[k] * in[r][c+k] ----
    auto hconv = [&](const float (&cf)[KS_]) {
        for (int task = tid; task < INW * 4; task += 256) {
            int r  = task >> 2;
            int cb = (task & 3) << 4;
            float w[32];
            if constexpr (PAD) {
                int gy = ty + r - HALO;
                if ((unsigned)gy < (unsigned)HW_) {
                    const float* src =
                        xsrc + ((size_t)b * HW_ + gy) * PROW + tx + cb;
                    #pragma unroll
                    for (int m = 0; m < 8; ++m)
                        *(float4*)(w + 4 * m) = *(const float4*)(src + 4 * m);
                } else {
                    #pragma unroll
                    for (int m = 0; m < 32; ++m) w[m] = 0.0f;
                }
            } else {
                #pragma unroll
                for (int m = 0; m < 8; ++m)
                    *(float4*)(w + 4 * m) =
                        *(const float4*)(s_in_arr + r * INS + cb + 4 * m);
            }
            float o[16];
            #pragma unroll
            for (int j = 0; j < 16; ++j) {
                float s = cf[0] * w[j];
                #pragma unroll
                for (int k = 1; k < KS_; ++k)
                    s = fmaf(cf[k], w[j + k], s);
                o[j] = s;
            }
            #pragma unroll
            for (int m = 0; m < 4; ++m)
                *(float4*)(s_h + r * SHS + cb + 4 * m) = *(float4*)(o + 4 * m);
        }
    };

    // ---- vertical pass: thread owns 1 col x 16 rows (R2-proven stores) ----
    const int c_out = tid & 63;           // wave-contiguous columns
    const int r0    = (tid >> 6) * 16;    // uniform per wave
    float acc[16];
    #pragma unroll
    for (int j = 0; j < 16; ++j) acc[j] = 0.0f;

    auto vconv = [&](const float (&cf)[KS_], float sgn) {
        #pragma unroll
        for (int r = 0; r < 16 + KS_ - 1; ++r) {   // 30 rows
            float v = s_h[(r0 + r) * SHS + c_out];
            #pragma unroll
            for (int j = 0; j < 16; ++j) {
                int k = r - j;
                if (k >= 0 && k < KS_)
                    acc[j] = fmaf(sgn * cf[k], v, acc[j]);
            }
        }
    };

    hconv(cA);
    __syncthreads();
    vconv(cA, 1.0f);
    __syncthreads();              // before overwriting s_h
    hconv(cB);                    // conv with -B  -> s_h = -hB
    __syncthreads();
    vconv(cB, -1.0f);             // (-1)(-B)(-hB) = -B*hB -> subtract

    // ---- store: 16 rows x 1 col, full-wave 256B contiguous segments ----
    float* ob = out + (((size_t)b * C_ + ch) * HW_ + (ty + r0)) * (size_t)HW_
                + tx + c_out;
    #pragma unroll
    for (int j = 0; j < 16; ++j)
        ob[(size_t)j * HW_] = acc[j];
}

__global__ __launch_bounds__(256, 6)
void sinc_conv_pad(const float* __restrict__ xpad,
                   const float* __restrict__ coefs,
                   float* __restrict__ out) {
    conv_body<true>(xpad, coefs, out);
}

__global__ __launch_bounds__(256, 3)
void sinc_conv_lds(const float* __restrict__ x,
                   const float* __restrict__ coefs,
                   float* __restrict__ out) {
    conv_body<false>(x, coefs, out);
}

extern "C" void kernel_launch(void* const* d_in, const int* in_sizes, int n_in,
                              void* d_out, int out_size, void* d_ws, size_t ws_size,
                              hipStream_t stream) {
    const float* x    = (const float*)d_in[0];
    const float* f1   = (const float*)d_in[1];
    const float* band = (const float*)d_in[2];
    float* ws   = (float*)d_ws;
    float* outp = (float*)d_out;

    hipLaunchKernelGGL(make_filters, dim3(1), dim3(64), 0, stream,
                       f1, band, ws);

    const int nblocks = B_ * C_ * (HW_ / TS) * (HW_ / TS);   // 65536
    const size_t need = (size_t)PADOFF * 4 + (size_t)B_ * HW_ * PROW * 4;

    if (ws_size >= need) {
        hipLaunchKernelGGL(pad_copy, dim3(4224), dim3(256), 0, stream, x, ws);
        hipLaunchKernelGGL(sinc_conv_pad, dim3(nblocks), dim3(256), 0, stream,
                           ws + PADOFF, ws, outp);
    } else {
        hipLaunchKernelGGL(sinc_conv_lds, dim3(nblocks), dim3(256), 0, stream,
                           x, ws, outp);
    }
}

// Round 5
// 582.316 us; speedup vs baseline: 2.8299x; 1.5270x over previous
//
#include <hip/hip_runtime.h>
#include <math.h>

#define B_     16
#define C_     64
#define HW_    512
#define KS_    15
#define HALO   7
#define PROW   528      // padded row: 8 + 512 + 8 (16B-aligned, b64-aligned windows)
#define PADOFF 2048     // float offset of padded image inside ws (8 KB for coefs)
#define YSEG   128      // rows per block
#define NSEG   4        // 512 / YSEG

typedef float vf2 __attribute__((ext_vector_type(2)));

// ---------------------------------------------------------------------------
// coefs[c*32 + i]      = F2*sinc(pi*F2*(i-7))*hamming[i]   (A)
// coefs[c*32 + 16 + i] = F1*sinc(pi*F1*(i-7))*hamming[i]   (B; subtracted via
//                         free FMA negate modifier in the conv kernel)
// ---------------------------------------------------------------------------
__global__ void make_filters(const float* __restrict__ f1,
                             const float* __restrict__ band,
                             float* __restrict__ coefs) {
    int c = threadIdx.x;
    if (c >= C_) return;
    float F1 = f1[c];
    float F2 = F1 + fabsf(band[c]);
    const float PI = 3.14159265358979323846f;
    #pragma unroll
    for (int i = 0; i < KS_; ++i) {
        float h = 0.54f - 0.46f * cosf((2.0f * PI / 14.0f) * (float)i);
        float y1, y2;
        if (i == HALO) {
            y1 = 1.0f; y2 = 1.0f;
        } else {
            float t  = (float)(i - HALO);
            float a1 = PI * F1 * t;
            float a2 = PI * F2 * t;
            y1 = sinf(a1) / a1;
            y2 = sinf(a2) / a2;
        }
        coefs[c * 32 + i]      = F2 * y2 * h;
        coefs[c * 32 + 16 + i] = F1 * y1 * h;
    }
}

// ---------------------------------------------------------------------------
// Column-padded input copy: ws[PADOFF + row*528 + 8 + gx] = x[row*512 + gx]
// (zero outside). row = b*512 + y.
// ---------------------------------------------------------------------------
__global__ void pad_copy(const float* __restrict__ x, float* __restrict__ ws) {
    int t   = blockIdx.x * 256 + threadIdx.x;   // 8192 rows * 132 quads
    int pc4 = t % 132;
    int row = t / 132;
    const float* src = x + (size_t)row * HW_;
    int gx0 = pc4 * 4 - 8;
    float v[4];
    #pragma unroll
    for (int e = 0; e < 4; ++e) {
        int gx = gx0 + e;
        v[e] = ((unsigned)gx < (unsigned)HW_) ? src[gx] : 0.0f;
    }
    *(float4*)(ws + PADOFF + (size_t)row * PROW + pc4 * 4) = *(float4*)v;
}

// ---------------------------------------------------------------------------
// Fused single-pass separable conv. One wave = one 128-col strip x YSEG rows
// of one (b,ch). Sweep rows once: stage padded row in per-wave LDS buffer
// (wave-synchronous, no barriers), hconv from 18-float window (9x b64),
// accumulate vconv via 15-deep register delay line, one output row completes
// per iteration. Input read once; no s_h buffer; LDS = 2.3 KB/block.
// ---------------------------------------------------------------------------
__global__ __launch_bounds__(256, 6)
void sinc_fused(const float* __restrict__ xpad,   // ws + PADOFF
                const float* __restrict__ coefs,
                float* __restrict__ out) {
    __shared__ __align__(16) float rowbuf[4][144];   // per-wave row buffer

    const int tid  = threadIdx.x;
    const int lane = tid & 63;
    const int wv   = tid >> 6;
    const int bid  = blockIdx.x;
    const int ch   = bid & 63;                 // channel fastest (L2 sharing)
    const int seg  = (bid >> 6) & (NSEG - 1);
    const int b    = bid >> 8;
    const int sx   = wv * 128;                 // strip base column
    const int y0   = seg * YSEG;

    // wave-uniform coefficients -> force SGPR
    float cA[KS_], cB[KS_];
    #pragma unroll
    for (int i = 0; i < KS_; ++i) {
        cA[i] = __uint_as_float(__builtin_amdgcn_readfirstlane(
                    __float_as_uint(coefs[ch * 32 + i])));
        cB[i] = __uint_as_float(__builtin_amdgcn_readfirstlane(
                    __float_as_uint(coefs[ch * 32 + 16 + i])));
    }

    // rowbuf[wv][o] = xpad_row[sx + o]  (o in [0,144) covers cols sx-8..sx+135)
    const float* xcol = xpad + (size_t)b * (HW_ * PROW) + sx + 2 * lane;
    float* sw = &rowbuf[wv][2 * lane];
    const float* swin = &rowbuf[wv][2 * lane];   // window: w[i] = x[c0-8+i]

    float acc0[KS_], acc1[KS_];                  // vconv delay line, 2 cols
    #pragma unroll
    for (int j = 0; j < KS_; ++j) { acc0[j] = 0.0f; acc1[j] = 0.0f; }

    float* outcol = out + (((size_t)b * C_ + ch) * HW_) * HW_ + sx + 2 * lane;

    // one-row software prefetch
    float2 nxt_m = make_float2(0.f, 0.f), nxt_e = make_float2(0.f, 0.f);
    {
        int y = y0 - HALO;
        if ((unsigned)y < (unsigned)HW_) {
            const float* xr = xcol + (size_t)y * PROW;
            nxt_m = *(const float2*)xr;
            if (lane < 8) nxt_e = *(const float2*)(xr + 128);
        }
    }

    #pragma unroll 5
    for (int y = y0 - HALO; y < y0 + YSEG + HALO; ++y) {   // 142 iterations
        const bool inb = (unsigned)y < (unsigned)HW_;
        float2 cur_m = nxt_m, cur_e = nxt_e;
        {   // prefetch next row (latency hidden under this row's FMAs)
            int yn = y + 1;
            if ((unsigned)yn < (unsigned)HW_) {
                const float* xr = xcol + (size_t)yn * PROW;
                nxt_m = *(const float2*)xr;
                if (lane < 8) nxt_e = *(const float2*)(xr + 128);
            }
        }
        if (inb) {
            // stage row (wave-synchronous: writes precede reads in-order)
            *(float2*)sw = cur_m;
            if (lane < 8) *(float2*)(sw + 128) = cur_e;
            // 18-float window, 9 aligned ds_read_b64
            float w[18];
            #pragma unroll
            for (int m = 0; m < 9; ++m)
                *(float2*)(w + 2 * m) = *(const float2*)(swin + 2 * m);
            // hconv for cols c0=sx+2*lane, c0+1:  hA(c0)=sum cA[k]*w[k+1] ...
            float hA0 = 0.f, hA1 = 0.f, hB0 = 0.f, hB1 = 0.f;
            #pragma unroll
            for (int k = 0; k < KS_; ++k) {
                hA0 = fmaf(cA[k], w[k + 1], hA0);
                hA1 = fmaf(cA[k], w[k + 2], hA1);
                hB0 = fmaf(cB[k], w[k + 1], hB0);
                hB1 = fmaf(cB[k], w[k + 2], hB1);
            }
            // vconv scatter: slot j holds output row (y-7+j), coef k=14-j
            #pragma unroll
            for (int j = 0; j < KS_; ++j) {
                acc0[j] = fmaf(cA[KS_ - 1 - j], hA0, acc0[j]);
                acc0[j] = fmaf(-cB[KS_ - 1 - j], hB0, acc0[j]);
                acc1[j] = fmaf(cA[KS_ - 1 - j], hA1, acc1[j]);
                acc1[j] = fmaf(-cB[KS_ - 1 - j], hB1, acc1[j]);
            }
        }
        const int yo = y - HALO;          // completed output row
        if (yo >= y0) {
            vf2 st; st.x = acc0[0]; st.y = acc1[0];
            __builtin_nontemporal_store(st,
                (vf2*)(outcol + (size_t)yo * HW_));
        }
        #pragma unroll
        for (int j = 0; j < KS_ - 1; ++j) {   // shift delay line
            acc0[j] = acc0[j + 1];
            acc1[j] = acc1[j + 1];
        }
        acc0[KS_ - 1] = 0.0f;
        acc1[KS_ - 1] = 0.0f;
    }
}

extern "C" void kernel_launch(void* const* d_in, const int* in_sizes, int n_in,
                              void* d_out, int out_size, void* d_ws, size_t ws_size,
                              hipStream_t stream) {
    const float* x    = (const float*)d_in[0];
    const float* f1   = (const float*)d_in[1];
    const float* band = (const float*)d_in[2];
    float* ws   = (float*)d_ws;
    float* outp = (float*)d_out;

    hipLaunchKernelGGL(make_filters, dim3(1), dim3(64), 0, stream,
                       f1, band, ws);
    hipLaunchKernelGGL(pad_copy, dim3(4224), dim3(256), 0, stream, x, ws);

    const int nblocks = B_ * NSEG * C_;   // 4096, ch fastest
    hipLaunchKernelGGL(sinc_fused, dim3(nblocks), dim3(256), 0, stream,
                       ws + PADOFF, ws, outp);
}

// Round 8
// 428.984 us; speedup vs baseline: 3.8414x; 1.3574x over previous
//
#include <hip/hip_runtime.h>
#include <math.h>

#define B_     16
#define C_     64
#define HW_    512
#define KS_    15
#define HALO   7
#define PROW   528      // padded row: 8 + 512 + 8 floats (16B-aligned)
#define PADOFF 2048     // float offset of padded image inside ws (8 KB coefs)
#define YSEG   128      // rows per wave
#define NSEG   4        // 512 / YSEG

typedef float vf4 __attribute__((ext_vector_type(4)));

// ---------------------------------------------------------------------------
// coefs[c*32 + i]      = F2*sinc(pi*F2*(i-7))*hamming[i]   (A)
// coefs[c*32 + 16 + i] = F1*sinc(pi*F1*(i-7))*hamming[i]   (B; subtracted via
//                         free FMA negate modifier in the conv kernel)
// ---------------------------------------------------------------------------
__global__ void make_filters(const float* __restrict__ f1,
                             const float* __restrict__ band,
                             float* __restrict__ coefs) {
    int c = threadIdx.x;
    if (c >= C_) return;
    float F1 = f1[c];
    float F2 = F1 + fabsf(band[c]);
    const float PI = 3.14159265358979323846f;
    #pragma unroll
    for (int i = 0; i < KS_; ++i) {
        float h = 0.54f - 0.46f * cosf((2.0f * PI / 14.0f) * (float)i);
        float y1, y2;
        if (i == HALO) {
            y1 = 1.0f; y2 = 1.0f;
        } else {
            float t  = (float)(i - HALO);
            float a1 = PI * F1 * t;
            float a2 = PI * F2 * t;
            y1 = sinf(a1) / a1;
            y2 = sinf(a2) / a2;
        }
        coefs[c * 32 + i]      = F2 * y2 * h;
        coefs[c * 32 + 16 + i] = F1 * y1 * h;
    }
}

// ---------------------------------------------------------------------------
// Column-padded input copy (R5-proven): xp[row*528 + gx + 8] = x[row*512+gx],
// zeros in cols [0,8) and [520,528). row = b*512 + y (no row padding).
// ---------------------------------------------------------------------------
__global__ void pad_copy(const float* __restrict__ x, float* __restrict__ xp) {
    int t   = blockIdx.x * 256 + threadIdx.x;   // 8192 rows * 132 quads
    int pc4 = t % 132;
    int row = t / 132;
    const float* src = x + (size_t)row * HW_;
    int gx0 = pc4 * 4 - 8;
    float v[4];
    #pragma unroll
    for (int e = 0; e < 4; ++e) {
        int gx = gx0 + e;
        v[e] = ((unsigned)gx < (unsigned)HW_) ? src[gx] : 0.0f;
    }
    *(vf4*)(xp + (size_t)row * PROW + pc4 * 4) = *(const vf4*)v;
}

// ---------------------------------------------------------------------------
// Fused single-pass separable conv, 4 cols/thread, NO LDS.
// One block = one wave = 256 cols x 128 rows of one (b,ch).
// Per row y: each lane loads its 20-float window xpad[c0 .. c0+19] directly
// from the padded global image (5x aligned dwordx4; L1/L2-resident since
// consecutive ch-blocks share rows), computes hA/hB (120 FMA), accumulates
// into the R5-proven 15-slot delay line (120 FMA), stores slot 0, shifts.
// Window math: h(c0+c) = sum_k cf[k]*x[c0+c-7+k]; x[g] = xpad[g+8]
//              -> = sum_k cf[k]*w[c+k+1] with w[m] = xpad[c0+m].
// ---------------------------------------------------------------------------
__global__ __launch_bounds__(64, 4)
void sinc_fused_g4(const float* __restrict__ xpad,
                   const float* __restrict__ coefs,
                   float* __restrict__ out) {
    const int lane = threadIdx.x;              // 64 threads = 1 wave
    const int bid  = blockIdx.x;
    const int ch   = bid & 63;                 // channel fastest (L2 sharing)
    const int xh   = (bid >> 6) & 1;
    const int seg  = (bid >> 7) & (NSEG - 1);
    const int b    = bid >> 9;
    const int sx   = xh * 256;
    const int y0   = seg * YSEG;
    const int c0   = sx + 4 * lane;

    // wave-uniform coefficients -> SGPR (R5-proven)
    float cA[KS_], cB[KS_];
    #pragma unroll
    for (int i = 0; i < KS_; ++i) {
        cA[i] = __uint_as_float(__builtin_amdgcn_readfirstlane(
                    __float_as_uint(coefs[ch * 32 + i])));
        cB[i] = __uint_as_float(__builtin_amdgcn_readfirstlane(
                    __float_as_uint(coefs[ch * 32 + 16 + i])));
    }

    const float* xw = xpad + (size_t)b * HW_ * PROW + c0;  // + y*PROW per row

    float acc[KS_][4];                          // delay line: slot j = row y-7+j
    #pragma unroll
    for (int j = 0; j < KS_; ++j)
        #pragma unroll
        for (int c = 0; c < 4; ++c) acc[j][c] = 0.0f;

    float* ob = out + ((size_t)(b * C_ + ch) * HW_) * HW_ + c0;

    #pragma unroll 2
    for (int y = y0 - HALO; y < y0 + YSEG + HALO; ++y) {   // 142 iterations
        if ((unsigned)y < (unsigned)HW_) {
            // 20-float window, 5 aligned global dwordx4 (L1/L2 hits)
            const float* p = xw + (size_t)y * PROW;
            float w[20] __attribute__((aligned(16)));
            #pragma unroll
            for (int m = 0; m < 5; ++m)
                *(vf4*)(w + 4 * m) = *(const vf4*)(p + 4 * m);
            // hconv for cols c0..c0+3
            float hA[4], hB[4];
            #pragma unroll
            for (int c = 0; c < 4; ++c) {
                hA[c] = cA[0] * w[c + 1];
                hB[c] = cB[0] * w[c + 1];
            }
            #pragma unroll
            for (int k = 1; k < KS_; ++k) {
                #pragma unroll
                for (int c = 0; c < 4; ++c) {
                    hA[c] = fmaf(cA[k], w[c + k + 1], hA[c]);
                    hB[c] = fmaf(cB[k], w[c + k + 1], hB[c]);
                }
            }
            // vconv delay line: slot j (output row y-7+j) needs coef cf[14-j]
            #pragma unroll
            for (int j = 0; j < KS_; ++j) {
                #pragma unroll
                for (int c = 0; c < 4; ++c) {
                    acc[j][c] = fmaf( cA[14 - j], hA[c], acc[j][c]);
                    acc[j][c] = fmaf(-cB[14 - j], hB[c], acc[j][c]);
                }
            }
        }
        // store completed output row yo = y - 7 (slot 0), then shift
        const int yo = y - HALO;
        if (yo >= y0) {
            vf4 st = {acc[0][0], acc[0][1], acc[0][2], acc[0][3]};
            __builtin_nontemporal_store(st, (vf4*)(ob + (size_t)yo * HW_));
        }
        #pragma unroll
        for (int j = 0; j < KS_ - 1; ++j)
            #pragma unroll
            for (int c = 0; c < 4; ++c)
                acc[j][c] = acc[j + 1][c];
        #pragma unroll
        for (int c = 0; c < 4; ++c) acc[KS_ - 1][c] = 0.0f;
    }
}

extern "C" void kernel_launch(void* const* d_in, const int* in_sizes, int n_in,
                              void* d_out, int out_size, void* d_ws, size_t ws_size,
                              hipStream_t stream) {
    const float* x    = (const float*)d_in[0];
    const float* f1   = (const float*)d_in[1];
    const float* band = (const float*)d_in[2];
    float* ws   = (float*)d_ws;
    float* outp = (float*)d_out;
    float* xp   = ws + PADOFF;

    hipLaunchKernelGGL(make_filters, dim3(1), dim3(64), 0, stream,
                       f1, band, ws);
    hipLaunchKernelGGL(pad_copy, dim3(4224), dim3(256), 0, stream, x, xp);

    const int nblocks = B_ * C_ * 2 * NSEG;    // 8192 one-wave blocks
    hipLaunchKernelGGL(sinc_fused_g4, dim3(nblocks), dim3(64), 0, stream,
                       xp, ws, outp);
}